// Round 12
// baseline (296.710 us; speedup 1.0000x reference)
//
#include <hip/hip_runtime.h>
#include <stdint.h>
#include <math.h>

#define D 128

typedef unsigned short u16;
typedef __attribute__((ext_vector_type(8))) short bf16x8;
typedef __attribute__((ext_vector_type(4))) float f32x4;
typedef __attribute__((ext_vector_type(2))) float f32x2;

union BU { uint4 u; bf16x8 s; };

// bf16 pack/unpack (RNE)
__device__ __forceinline__ unsigned f2bf_pk(float a, float b) {
    union { float f; unsigned u; } x, y; x.f = a; y.f = b;
    unsigned ra = x.u + 0x7FFF + ((x.u >> 16) & 1);
    unsigned rb = y.u + 0x7FFF + ((y.u >> 16) & 1);
    return (ra >> 16) | (rb & 0xFFFF0000u);
}
__device__ __forceinline__ u16 f2bf(float f) {
    union { float f; unsigned u; } x; x.f = f;
    unsigned r = x.u + 0x7FFF + ((x.u >> 16) & 1);
    return (u16)(r >> 16);
}
__device__ __forceinline__ f32x2 bf2f2v(unsigned u) {
    union { unsigned w[2]; f32x2 v; } t;
    t.w[0] = u << 16; t.w[1] = u & 0xFFFF0000u;
    return t.v;
}
__device__ __forceinline__ f32x2 vmax0(f32x2 a) {
    return __builtin_elementwise_max(a, (f32x2)(0.f));
}
// pad to batch granularity 4 (0 allowed for isolated nodes)
__device__ __forceinline__ int padded4(int deg) {
    return (deg + 3) & ~3;
}

// ---- CSR build, XCD-partitioned: block b handles partition b&7 = dst range [p*N8,(p+1)*N8) ----
// All atomics/stores for a node come from one partition => XCD-local L2 lines (heuristic only).

__global__ __launch_bounds__(256) void k_degree_part(const int* __restrict__ dst, int E,
                                                     int* __restrict__ hist, int N8, int G4) {
    int b = blockIdx.x;
    int part = b & 7;
    int i = (b >> 3) * 256 + threadIdx.x;
    int lo = part * N8;
    if (i < G4) {
        int4 d = ((const int4*)dst)[i];
        if ((unsigned)(d.x - lo) < (unsigned)N8) atomicAdd(&hist[d.x], 1);
        if ((unsigned)(d.y - lo) < (unsigned)N8) atomicAdd(&hist[d.y], 1);
        if ((unsigned)(d.z - lo) < (unsigned)N8) atomicAdd(&hist[d.z], 1);
        if ((unsigned)(d.w - lo) < (unsigned)N8) atomicAdd(&hist[d.w], 1);
    }
    if (b == 0 && threadIdx.x == 0) {
        for (int j = G4 * 4; j < E; ++j) atomicAdd(&hist[dst[j]], 1);
    }
}

// per node: dinv; block sums of padded degree (hist == degi)
__global__ __launch_bounds__(256) void k_dinv_bsum(const int* __restrict__ hist,
                                                   float* __restrict__ dinv, int* __restrict__ bsum, int N) {
    __shared__ int ws[4];
    int t = threadIdx.x;
    int i = blockIdx.x * 256 + t;
    int pd = 0;
    if (i < N) {
        int run = hist[i];
        dinv[i] = rsqrtf((float)run + 1.0f);
        pd = padded4(run);
    }
    int v = pd;
#pragma unroll
    for (int off = 1; off < 64; off <<= 1) v += __shfl_xor(v, off, 64);
    if ((t & 63) == 0) ws[t >> 6] = v;
    __syncthreads();
    if (t == 0) bsum[blockIdx.x] = ws[0] + ws[1] + ws[2] + ws[3];
}

__global__ __launch_bounds__(1024) void k_boff_wprep(const int* __restrict__ bsum, int* __restrict__ boff,
                                                     int nb, int* __restrict__ prow, int N,
                                                     const float* __restrict__ W2, const float* __restrict__ Wlin,
                                                     unsigned* __restrict__ wswz) {
    int t = threadIdx.x;
    if (blockIdx.x == 0) {
        __shared__ int s[1024];
        s[t] = (t < nb) ? bsum[t] : 0;
        __syncthreads();
        for (int off = 1; off < 1024; off <<= 1) {
            int v = (t >= off) ? s[t - off] : 0;
            __syncthreads();
            s[t] += v;
            __syncthreads();
        }
        if (t < nb) boff[t] = (t == 0) ? 0 : s[t - 1];
        if (t == 0) prow[N] = s[1023];
    } else {
        int tid = (blockIdx.x - 1) * 1024 + t;       // 0..24575 = 3*8192
        int m = tid >> 13;
        int r = tid & 8191;
        int jp = r & 3;
        int lane = (r >> 2) & 63;
        int ct = (r >> 8) & 7;
        int kc = r >> 11;
        int k0 = kc * 32 + (lane >> 4) * 8 + 2 * jp;
        int n = ct * 16 + (lane & 15);
        const float* srcp = (m == 0) ? W2 : (Wlin + (m - 1) * 16384);
        wswz[tid] = f2bf_pk(srcp[k0 * 128 + n], srcp[(k0 + 1) * 128 + n]);
    }
}

__global__ __launch_bounds__(256) void k_scan_final(const int* __restrict__ hist, const int* __restrict__ boff,
                                                    int* __restrict__ prow, int N) {
    __shared__ int s[256];
    int t = threadIdx.x;
    int i = blockIdx.x * 256 + t;
    int pd = (i < N) ? padded4(hist[i]) : 0;
    s[t] = pd;
    __syncthreads();
    for (int off = 1; off < 256; off <<= 1) {
        int v = (t >= off) ? s[t - off] : 0;
        __syncthreads();
        s[t] += v;
        __syncthreads();
    }
    if (i < N) prow[i] = boff[blockIdx.x] + ((t == 0) ? 0 : s[t - 1]);
}

// ---- Merged dispatch: XCD-partitioned scatter | pad fill | xform1 ----
// blocks [0, sgrid)          : scatter edges of partition b&7 into padded CSR
// blocks [sgrid, sgrid+nb)   : fill pad slots with {N,0}; first also fills tail sentinels
// blocks [sgrid+nb, ...+xb)  : g1 = bf16(dinv * (x @ W1)) (+ zero sentinel row)

__global__ __launch_bounds__(256) void k_scatter_fill_xform(
        const int* __restrict__ src, const int* __restrict__ dst, int E,
        const int* __restrict__ prow, int* __restrict__ cursor, const int* __restrict__ hist,
        int2* __restrict__ coleid, int N, int N8, int G4, int sgrid, int nb,
        const float* __restrict__ x, const float* __restrict__ W1,
        const float* __restrict__ dinv, unsigned* __restrict__ g) {
    __shared__ float Ws[8 * D];
    int t = threadIdx.x;
    int b = blockIdx.x;
    if (b < sgrid) {
        int part = b & 7;
        int i = (b >> 3) * 256 + t;
        int lo = part * N8;
        if (i < G4) {
            int4 d = ((const int4*)dst)[i];
            bool h0 = (unsigned)(d.x - lo) < (unsigned)N8;
            bool h1 = (unsigned)(d.y - lo) < (unsigned)N8;
            bool h2 = (unsigned)(d.z - lo) < (unsigned)N8;
            bool h3 = (unsigned)(d.w - lo) < (unsigned)N8;
            if (h0 | h1 | h2 | h3) {
                int4 s4 = ((const int4*)src)[i];
                int e = i * 4;
                int off;
                if (h0) { off = atomicAdd(&cursor[d.x], 1); coleid[prow[d.x] + off] = make_int2(s4.x, e + 0); }
                if (h1) { off = atomicAdd(&cursor[d.y], 1); coleid[prow[d.y] + off] = make_int2(s4.y, e + 1); }
                if (h2) { off = atomicAdd(&cursor[d.z], 1); coleid[prow[d.z] + off] = make_int2(s4.z, e + 2); }
                if (h3) { off = atomicAdd(&cursor[d.w], 1); coleid[prow[d.w] + off] = make_int2(s4.w, e + 3); }
            }
        }
        if (b == 0 && t == 0) {
            for (int j = G4 * 4; j < E; ++j) {
                int d = dst[j];
                int off = atomicAdd(&cursor[d], 1);
                coleid[prow[d] + off] = make_int2(src[j], j);
            }
        }
    } else if (b < sgrid + nb) {
        int n = (b - sgrid) * 256 + t;
        if (n < N) {
            int lo = prow[n];
            int deg = hist[n];
            int pd = padded4(deg);
            for (int j = deg; j < pd; ++j) coleid[lo + j] = make_int2(N, 0);
        }
        if (b == sgrid && t == 0) {
            int P = prow[N];
            for (int j = 0; j < 16; ++j) coleid[P + j] = make_int2(N, 0);
        }
    } else {
        int xb0 = b - sgrid - nb;
        for (int i = t; i < 8 * D; i += 256) Ws[i] = W1[i];
        __syncthreads();
        int node = xb0 * 4 + (t >> 6);
        int l = t & 63;
        if (node < N) {
            float s0 = 0.f, s1 = 0.f;
#pragma unroll
            for (int k = 0; k < 8; ++k) {
                float xv = x[node * 8 + k];
                s0 += xv * Ws[k * D + 2 * l];
                s1 += xv * Ws[k * D + 2 * l + 1];
            }
            float di = dinv[node];
            g[node * 64 + l] = f2bf_pk(s0 * di, s1 * di);
        }
        if (xb0 == 0 && t < 64) g[(size_t)N * 64 + t] = 0;   // zero sentinel row
    }
}

// ---- Fused aggregation + MFMA GEMM ----

#define HROW 136   // u16 per LDS row (128 + 8 pad -> 272 B row stride)

template <bool DUAL>
__global__ __launch_bounds__(256) void k_aggemm(const uint4* __restrict__ g, const int* __restrict__ prow,
                                                const int2* __restrict__ coleid, const float* __restrict__ dinv,
                                                const float* __restrict__ biasH,
                                                const uint4* __restrict__ wB0, const uint4* __restrict__ wB1,
                                                const float* __restrict__ bias1,
                                                u16* __restrict__ out0, u16* __restrict__ out1, int N) {
    __shared__ u16 hs[16 * HROW];
    int t = threadIdx.x;
    int wv = t >> 6;
    int lane = t & 63;
    int sub = lane >> 4;
    int r = lane & 15;
    int base = blockIdx.x * 16;

    // ---- aggregation phase: 4 nodes per wave ----
    for (int nd = 0; nd < 4; ++nd) {
        int i = base + wv * 4 + nd;
        int lrow = wv * 4 + nd;
        if (i < N) {
            f32x2 acc2[4];
#pragma unroll
            for (int j = 0; j < 4; ++j) acc2[j] = (f32x2)(0.f);
            int lo = prow[i], hiP = prow[i + 1];
            int idx = lo + sub;
            int c0 = coleid[idx].x;
            int c1 = (idx + 4 < hiP) ? coleid[idx + 4].x : N;
            int c2 = (idx + 8 < hiP) ? coleid[idx + 8].x : N;
            uint4 v0 = g[c0 * 16 + r];
            uint4 v1 = g[c1 * 16 + r];
            for (int k = lo; k < hiP; k += 4) {
                int c3 = (idx + 12 < hiP) ? coleid[idx + 12].x : N;
                uint4 v2 = g[c2 * 16 + r];
                acc2[0] += bf2f2v(v0.x);
                acc2[1] += bf2f2v(v0.y);
                acc2[2] += bf2f2v(v0.z);
                acc2[3] += bf2f2v(v0.w);
                v0 = v1; v1 = v2; c2 = c3; idx += 4;
            }
#pragma unroll
            for (int j = 0; j < 4; ++j) {
                acc2[j].x += __shfl_xor(acc2[j].x, 16, 64);
                acc2[j].y += __shfl_xor(acc2[j].y, 16, 64);
                acc2[j].x += __shfl_xor(acc2[j].x, 32, 64);
                acc2[j].y += __shfl_xor(acc2[j].y, 32, 64);
            }
            if (sub == 0) {
                uint4 sv = g[i * 16 + r];   // self term
                acc2[0] += bf2f2v(sv.x);
                acc2[1] += bf2f2v(sv.y);
                acc2[2] += bf2f2v(sv.z);
                acc2[3] += bf2f2v(sv.w);
                float di = dinv[i];
                float4 b0 = ((const float4*)biasH)[r * 2];
                float4 b1v = ((const float4*)biasH)[r * 2 + 1];
                float r0 = fmaxf(acc2[0].x * di + b0.x, 0.f);
                float r1 = fmaxf(acc2[0].y * di + b0.y, 0.f);
                float r2 = fmaxf(acc2[1].x * di + b0.z, 0.f);
                float r3 = fmaxf(acc2[1].y * di + b0.w, 0.f);
                float r4 = fmaxf(acc2[2].x * di + b1v.x, 0.f);
                float r5 = fmaxf(acc2[2].y * di + b1v.y, 0.f);
                float r6 = fmaxf(acc2[3].x * di + b1v.z, 0.f);
                float r7 = fmaxf(acc2[3].y * di + b1v.w, 0.f);
                uint4 o;
                o.x = f2bf_pk(r0, r1);
                o.y = f2bf_pk(r2, r3);
                o.z = f2bf_pk(r4, r5);
                o.w = f2bf_pk(r6, r7);
                *(uint4*)(hs + lrow * HROW + r * 8) = o;
            }
        } else if (sub == 0) {
            *(uint4*)(hs + lrow * HROW + r * 8) = make_uint4(0, 0, 0, 0);
        }
    }
    __syncthreads();

    // ---- GEMM phase: wave wv handles column-tiles ct0, ct0+1 ----
    int quad = lane >> 4;
    int l15 = lane & 15;
    int ct0 = wv * 2;

    f32x4 accA[2], accB[2];
#pragma unroll
    for (int q = 0; q < 2; ++q) { accA[q] = (f32x4){0.f, 0.f, 0.f, 0.f}; accB[q] = (f32x4){0.f, 0.f, 0.f, 0.f}; }

    const uint4* hrow = (const uint4*)(hs + l15 * HROW);
#pragma unroll
    for (int kc = 0; kc < 4; ++kc) {
        BU a; a.u = hrow[kc * 4 + quad];
#pragma unroll
        for (int q = 0; q < 2; ++q) {
            BU b0; b0.u = wB0[(kc * 8 + ct0 + q) * 64 + lane];
            accA[q] = __builtin_amdgcn_mfma_f32_16x16x32_bf16(a.s, b0.s, accA[q], 0, 0, 0);
            if (DUAL) {
                BU b1; b1.u = wB1[(kc * 8 + ct0 + q) * 64 + lane];
                accB[q] = __builtin_amdgcn_mfma_f32_16x16x32_bf16(a.s, b1.s, accB[q], 0, 0, 0);
            }
        }
    }
#pragma unroll
    for (int reg = 0; reg < 4; ++reg) {
        int node = base + quad * 4 + reg;
        if (node >= N) continue;
        float sc = DUAL ? 1.0f : dinv[node];
#pragma unroll
        for (int q = 0; q < 2; ++q) {
            int colj = (ct0 + q) * 16 + l15;
            out0[(size_t)node * 128 + colj] = f2bf(accA[q][reg] * sc);
            if (DUAL) out1[(size_t)node * 128 + colj] = f2bf(accB[q][reg] + bias1[colj]);
        }
    }
    if (blockIdx.x == 0 && t < 64) ((unsigned*)out0)[(size_t)N * 64 + t] = 0;   // zero sentinel row
}

// ---- Edge output: padded CSR, depth-2 pipeline, packed f32x2 math ----

__global__ __launch_bounds__(256) void k_edge(const uint4* __restrict__ a, const uint4* __restrict__ c,
                                              const int* __restrict__ prow, const int* __restrict__ degi,
                                              const int2* __restrict__ coleid,
                                              const float* __restrict__ Wfin, const float* __restrict__ bfin,
                                              float* __restrict__ out, int N) {
    int wave = (blockIdx.x * blockDim.x + threadIdx.x) >> 6;
    int lane = threadIdx.x & 63;
    if (wave >= N) return;
    int d = wave;
    int g = lane >> 4;
    int r = lane & 15;

    f32x2 wf0v[4], wf1v[4];
    const float4* wvp = (const float4*)Wfin;
#pragma unroll
    for (int q = 0; q < 4; ++q) {
        float4 m = wvp[r * 4 + q];
        wf0v[q] = (f32x2){m.x, m.z};
        wf1v[q] = (f32x2){m.y, m.w};
    }
    float bf0 = bfin[0], bf1 = bfin[1];

    f32x2 cf2[4];
    {
        uint4 cv = c[d * 16 + r];
        cf2[0] = bf2f2v(cv.x);
        cf2[1] = bf2f2v(cv.y);
        cf2[2] = bf2f2v(cv.z);
        cf2[3] = bf2f2v(cv.w);
    }

    int lo = prow[d], hiP = prow[d + 1];
    int deg = degi[d];

    int idx = lo + g;
    int2 q0 = coleid[idx];
    int2 q1 = coleid[idx + 4];
    int c1 = (idx + 4 < hiP) ? q1.x : N;
    int2 q2 = coleid[idx + 8];
    int c2 = (idx + 8 < hiP) ? q2.x : N;
    int e0 = q0.y, e1 = q1.y, e2 = q2.y;
    uint4 v0 = a[q0.x * 16 + r];
    uint4 v1 = a[c1 * 16 + r];

    int rel = g;
    for (int k = lo; k < hiP; k += 4) {
        int2 q3 = coleid[idx + 12];
        int c3 = (idx + 12 < hiP) ? q3.x : N;
        uint4 v2 = a[c2 * 16 + r];
        f32x2 p0v = (f32x2)(0.f), p1v = (f32x2)(0.f);
        f32x2 z;
        z = vmax0(bf2f2v(v0.x) + cf2[0]); p0v += z * wf0v[0]; p1v += z * wf1v[0];
        z = vmax0(bf2f2v(v0.y) + cf2[1]); p0v += z * wf0v[1]; p1v += z * wf1v[1];
        z = vmax0(bf2f2v(v0.z) + cf2[2]); p0v += z * wf0v[2]; p1v += z * wf1v[2];
        z = vmax0(bf2f2v(v0.w) + cf2[3]); p0v += z * wf0v[3]; p1v += z * wf1v[3];
        float p0 = p0v.x + p0v.y;
        float p1 = p1v.x + p1v.y;
        p0 += __shfl_xor(p0, 1, 64);
        p0 += __shfl_xor(p0, 2, 64);
        p0 += __shfl_xor(p0, 4, 64);
        p0 += __shfl_xor(p0, 8, 64);
        p1 += __shfl_xor(p1, 1, 64);
        p1 += __shfl_xor(p1, 2, 64);
        p1 += __shfl_xor(p1, 4, 64);
        p1 += __shfl_xor(p1, 8, 64);
        if (r == 0 && rel < deg) {
            float l0 = p0 + bf0, l1 = p1 + bf1;
            float m = fmaxf(l0, l1);
            float lse = m + __logf(__expf(l0 - m) + __expf(l1 - m));
            *((float2*)(out + 2 * (size_t)e0)) = make_float2(l0 - lse, l1 - lse);
        }
        v0 = v1; v1 = v2;
        e0 = e1; e1 = e2; e2 = q3.y;
        c2 = c3; idx += 4; rel += 4;
    }
}

extern "C" void kernel_launch(void* const* d_in, const int* in_sizes, int n_in,
                              void* d_out, int out_size, void* d_ws, size_t ws_size,
                              hipStream_t stream) {
    const float* x     = (const float*)d_in[0];
    const int*   ei    = (const int*)d_in[1];
    const float* W1    = (const float*)d_in[2];
    const float* b1    = (const float*)d_in[3];
    const float* W2    = (const float*)d_in[4];
    const float* b2    = (const float*)d_in[5];
    const float* Wlin1 = (const float*)d_in[6];
    const float* blin1 = (const float*)d_in[7];
    const float* Wfin  = (const float*)d_in[8];
    const float* bfin  = (const float*)d_in[9];
    float* out = (float*)d_out;

    int N = in_sizes[0] / 8;
    int E = in_sizes[1] / 2;
    const int* src = ei;
    const int* dst = ei + E;
    int nb = (N + 255) / 256;
    int xb = (N + 3) / 4;
    int N8 = (N + 7) / 8;
    int G4 = E >> 2;
    int ngc = (G4 + 255) / 256;
    int sgrid = ngc * 8;        // scatter/degree grid: chunk x 8 partitions

    char* w = (char*)d_ws;
    int* hist = (int*)w;      w += (size_t)N * 4;   // degree (also degi for k_edge)
    int* cursor = (int*)w;    w += (size_t)N * 4;
    int* prow = (int*)w;      w += (size_t)(N + 1) * 4;
    float* dinv = (float*)w;  w += (size_t)N * 4;
    int* bsum = (int*)w;      w += (size_t)nb * 4;
    int* boff = (int*)w;      w += (size_t)nb * 4;
    w = (char*)(((uintptr_t)w + 255) & ~(uintptr_t)255);
    int2* coleid = (int2*)w;  w += ((size_t)E + 8 * (size_t)N + 64) * 8;
    unsigned* wswz = (unsigned*)w; w += (size_t)3 * 8192 * 4;
    unsigned* bufG = (unsigned*)w; w += (size_t)(N + 1) * 64 * 4;   // g1 + sentinel
    unsigned* bufA = (unsigned*)w; w += (size_t)(N + 1) * 64 * 4;   // a + sentinel
    unsigned* bufC = (unsigned*)w; w += (size_t)N * 64 * 4;         // c
    unsigned* bufG2 = (unsigned*)w; w += (size_t)(N + 1) * 64 * 4;  // g2 + sentinel

    hipMemsetAsync(hist, 0, (size_t)2 * N * 4, stream);   // hist + cursor contiguous

    k_degree_part<<<sgrid, 256, 0, stream>>>(dst, E, hist, N8, G4);
    k_dinv_bsum<<<nb, 256, 0, stream>>>(hist, dinv, bsum, N);
    k_boff_wprep<<<25, 1024, 0, stream>>>(bsum, boff, nb, prow, N, W2, Wlin1, wswz);
    k_scan_final<<<nb, 256, 0, stream>>>(hist, boff, prow, N);
    // merged: XCD-partitioned scatter | pad fill | layer-1 transform
    k_scatter_fill_xform<<<sgrid + nb + xb, 256, 0, stream>>>(src, dst, E, prow, cursor, hist,
                                                              coleid, N, N8, G4, sgrid, nb,
                                                              x, W1, dinv, bufG);

    int ablocks = (N + 15) / 16;
    // fused: agg(g1)->h1 -> GEMM W2 -> g2 (dinv-scaled) + sentinel
    k_aggemm<false><<<ablocks, 256, 0, stream>>>((const uint4*)bufG, prow, coleid, dinv, b1,
                                                 (const uint4*)wswz, nullptr, nullptr,
                                                 (u16*)bufG2, nullptr, N);
    // fused: agg(g2)->h2 -> dual GEMM -> a (+sentinel), c (+blin1)
    k_aggemm<true><<<ablocks, 256, 0, stream>>>((const uint4*)bufG2, prow, coleid, dinv, b2,
                                                (const uint4*)(wswz + 8192), (const uint4*)(wswz + 16384),
                                                blin1, (u16*)bufA, (u16*)bufC, N);

    k_edge<<<(N + 3) / 4, 256, 0, stream>>>((const uint4*)bufA, (const uint4*)bufC,
                                            prow, hist, coleid, Wfin, bfin, out, N);
}